// Round 3
// baseline (78.440 us; speedup 1.0000x reference)
//
#include <hip/hip_runtime.h>
#include <math.h>

#define BB 32
#define NN 1024

typedef __attribute__((ext_vector_type(4))) _Float16 h4;   // 8 bytes

// ===========================================================================
// Column-split structure for all y-sweeps:
//   grid (B=32, 16) = 512 blocks, block 256 = 16 col-threads (ct, 4 cols each)
//   x 16 row-groups (rg, 64 rows each). Cross-rowgroup reduction in LDS;
//   every pass finalizes in-block (no global partials).
// Pass 1 reads fp32 y and emits a 64 MB fp16 copy (y16) that passes 2/3 read.
// ===========================================================================

// ---------------------------------------------------------------------------
// kA (pass 1): deg = colsum(y) + diag fill -> dinv, dfill;  y16 = (fp16)y
// ---------------------------------------------------------------------------
__global__ __launch_bounds__(256) void kA(const float* __restrict__ y,
                                          _Float16* __restrict__ y16,
                                          float* __restrict__ dinv,
                                          float* __restrict__ dfill) {
    __shared__ float red[16 * 68];      // [rg][68] pad: 2-way reads (free)
    const int b = blockIdx.x, by = blockIdx.y;
    const int t = threadIdx.x, ct = t & 15, rg = t >> 4;
    const int j0 = by * 64 + ct * 4;
    const size_t boff = (size_t)b * NN * NN + (size_t)(rg * 64) * NN + j0;
    const float* base = y + boff;
    _Float16* obase = y16 + boff;
    float4 acc = make_float4(0.f, 0.f, 0.f, 0.f);
#pragma unroll 8
    for (int i = 0; i < 64; ++i) {
        float4 v = *(const float4*)(base + (size_t)i * NN);
        acc.x += v.x; acc.y += v.y; acc.z += v.z; acc.w += v.w;
        h4 hv = { (_Float16)v.x, (_Float16)v.y, (_Float16)v.z, (_Float16)v.w };
        *(h4*)(obase + (size_t)i * NN) = hv;
    }
    *(float4*)&red[rg * 68 + ct * 4] = acc;
    __syncthreads();
    if (t < 64) {
        float s = 0.f;
#pragma unroll
        for (int r = 0; r < 16; ++r) s += red[r * 68 + t];
        const int j = by * 64 + t;
        const float dia = y[((size_t)b * NN + j) * NN + j];
        const float fill = (dia == 0.0f) ? 1.0f : 0.0f;
        const float deg = s + fill;
        const float dv = (deg > 0.0f) ? (1.0f / sqrtf(deg)) : 0.0f;
        dinv[b * NN + j] = dv;
        dfill[b * NN + j] = dv * fill;
    }
}

// ---------------------------------------------------------------------------
// kB (pass 2): cs[j] = dinv[j]*(sum_i dinv[i]*y[i,j] + dfill[j]);
//              hW2[j,g] = sum_f relu(cs*W1[f]+b1[f]) * W2[f,g]
// ---------------------------------------------------------------------------
__global__ __launch_bounds__(256) void kB(const _Float16* __restrict__ y16,
                                          const float* __restrict__ dinv,
                                          const float* __restrict__ dfill,
                                          const float* __restrict__ W1,
                                          const float* __restrict__ b1,
                                          const float* __restrict__ W2,
                                          float* __restrict__ hW2) {
    __shared__ float red[16 * 68];
    __shared__ float csb[64];
    const int b = blockIdx.x, by = blockIdx.y;
    const int t = threadIdx.x, ct = t & 15, rg = t >> 4;
    const int j0 = by * 64 + ct * 4;
    const _Float16* base = y16 + (size_t)b * NN * NN + (size_t)(rg * 64) * NN + j0;
    const float* dvp = dinv + b * NN + rg * 64;
    float4 acc = make_float4(0.f, 0.f, 0.f, 0.f);
#pragma unroll 8
    for (int i = 0; i < 64; ++i) {
        const float di = dvp[i];
        h4 hv = *(const h4*)(base + (size_t)i * NN);
        acc.x += (float)hv.x * di; acc.y += (float)hv.y * di;
        acc.z += (float)hv.z * di; acc.w += (float)hv.w * di;
    }
    *(float4*)&red[rg * 68 + ct * 4] = acc;
    __syncthreads();
    if (t < 64) {
        float s = 0.f;
#pragma unroll
        for (int r = 0; r < 16; ++r) s += red[r * 68 + t];
        const int idx = b * NN + by * 64 + t;
        csb[t] = dinv[idx] * (s + dfill[idx]);
    }
    __syncthreads();
    // 256 threads = 64 cols x 4 g-quarters
    const int q = t >> 2, gq = t & 3;
    const float cs = csb[q];
    float4 h = make_float4(0.f, 0.f, 0.f, 0.f);
#pragma unroll
    for (int f = 0; f < 64; ++f) {
        float x1 = fmaf(cs, W1[f], b1[f]);
        x1 = x1 > 0.f ? x1 : 0.f;
        float4 w = *(const float4*)(W2 + f * 16 + gq * 4);
        h.x += x1 * w.x; h.y += x1 * w.y; h.z += x1 * w.z; h.w += x1 * w.w;
    }
    const int j = by * 64 + q;
    *(float4*)(hW2 + ((size_t)(b * NN + j)) * 16 + gq * 4) = h;
}

// ---------------------------------------------------------------------------
// kC (pass 3): out2[j,g] = dinv[j]*(sum_i dinv[i]*y[i,j]*hW2[i,g]
//                                   + dfill[j]*hW2[j,g]) + b2[g];
//              rowmax[j] = max_g out2[j,g].   No global partials.
// LDS reduce layout: float4 slot (rg*256 + ct*16 + p), p = (g+ct+rg)&15
// ---------------------------------------------------------------------------
__global__ __launch_bounds__(256) void kC(const _Float16* __restrict__ y16,
                                          const float* __restrict__ dinv,
                                          const float* __restrict__ dfill,
                                          const float* __restrict__ hW2,
                                          const float* __restrict__ b2,
                                          float* __restrict__ rowmax) {
    __shared__ float red[16 * 16 * 16 * 4];   // 64 KB
    const int b = blockIdx.x, by = blockIdx.y;
    const int t = threadIdx.x, ct = t & 15, rg = t >> 4;
    const int j0 = by * 64 + ct * 4;
    const _Float16* base = y16 + (size_t)b * NN * NN + (size_t)(rg * 64) * NN + j0;
    const float* dvp = dinv + b * NN + rg * 64;
    const float* hp = hW2 + ((size_t)(b * NN + rg * 64)) * 16;

    float4 acc[16];
#pragma unroll
    for (int g = 0; g < 16; ++g) acc[g] = make_float4(0.f, 0.f, 0.f, 0.f);

#pragma unroll 4
    for (int i = 0; i < 64; ++i) {
        h4 hv = *(const h4*)(base + (size_t)i * NN);
        const float di = dvp[i];
        const float4* hr = (const float4*)(hp + (size_t)i * 16);
        float4 h0 = hr[0], h1 = hr[1], h2 = hr[2], h3 = hr[3];
        float4 a;
        a.x = (float)hv.x * di; a.y = (float)hv.y * di;
        a.z = (float)hv.z * di; a.w = (float)hv.w * di;
#define STEP(G, HS) acc[G].x += a.x * (HS); acc[G].y += a.y * (HS); \
                    acc[G].z += a.z * (HS); acc[G].w += a.w * (HS);
        STEP(0, h0.x)  STEP(1, h0.y)  STEP(2, h0.z)  STEP(3, h0.w)
        STEP(4, h1.x)  STEP(5, h1.y)  STEP(6, h1.z)  STEP(7, h1.w)
        STEP(8, h2.x)  STEP(9, h2.y)  STEP(10, h2.z) STEP(11, h2.w)
        STEP(12, h3.x) STEP(13, h3.y) STEP(14, h3.z) STEP(15, h3.w)
#undef STEP
    }
#pragma unroll
    for (int g = 0; g < 16; ++g) {
        const int p = (g + ct + rg) & 15;
        *(float4*)&red[(rg * 256 + ct * 16 + p) * 4] = acc[g];
    }
    __syncthreads();
    const int q = t >> 2, gq = t & 3;
    const int cti = q >> 2, kk = q & 3;
    const int j = by * 64 + q;
    const int idx = b * NN + j;
    const float dv = dinv[idx], df = dfill[idx];
    const float* hj = hW2 + (size_t)idx * 16;
    float m = -3.4e38f;
#pragma unroll
    for (int e = 0; e < 4; ++e) {
        const int g = gq * 4 + e;
        float s = 0.f;
#pragma unroll
        for (int r = 0; r < 16; ++r) {
            const int p = (g + cti + r) & 15;
            s += red[(r * 256 + cti * 16 + p) * 4 + kk];
        }
        const float ov = dv * (s + df * hj[g]) + b2[g];
        m = fmaxf(m, ov);
    }
    m = fmaxf(m, __shfl_xor(m, 1));
    m = fmaxf(m, __shfl_xor(m, 2));
    if ((t & 3) == 0) rowmax[idx] = m;
}

// ---------------------------------------------------------------------------
// k5: head — (B,N) @ Wm1(N,32) + bm1 -> @ Wm2(32,16) + bm2.  1 block / batch.
// ---------------------------------------------------------------------------
__global__ __launch_bounds__(1024) void k5_head(const float* __restrict__ rowmax,
                                                const float* __restrict__ Wm1,
                                                const float* __restrict__ bm1,
                                                const float* __restrict__ Wm2,
                                                const float* __restrict__ bm2,
                                                float* __restrict__ out) {
    __shared__ float sm[NN];
    __shared__ float p[32 * 32];
    __shared__ float z[32];
    const int b = blockIdx.x, t = threadIdx.x;
    sm[t] = rowmax[(size_t)b * NN + t];
    __syncthreads();
    const int k = t & 31, c = t >> 5;
    float acc = 0.f;
#pragma unroll 8
    for (int qq = 0; qq < 32; ++qq) {
        const int j = c * 32 + qq;
        acc += sm[j] * Wm1[j * 32 + k];
    }
    p[c * 32 + k] = acc;
    __syncthreads();
    if (t < 32) {
        float s = 0.f;
#pragma unroll
        for (int c2 = 0; c2 < 32; ++c2) s += p[c2 * 32 + t];
        z[t] = s + bm1[t];
    }
    __syncthreads();
    if (t < 16) {
        float s = 0.f;
#pragma unroll
        for (int k2 = 0; k2 < 32; ++k2) s += z[k2] * Wm2[k2 * 16 + t];
        out[b * 16 + t] = s + bm2[t];
    }
}

// ---------------------------------------------------------------------------
extern "C" void kernel_launch(void* const* d_in, const int* in_sizes, int n_in,
                              void* d_out, int out_size, void* d_ws, size_t ws_size,
                              hipStream_t stream) {
    const float* y   = (const float*)d_in[0];
    const float* W1  = (const float*)d_in[1];
    const float* b1  = (const float*)d_in[2];
    const float* W2  = (const float*)d_in[3];
    const float* b2  = (const float*)d_in[4];
    const float* Wm1 = (const float*)d_in[5];
    const float* bm1 = (const float*)d_in[6];
    const float* Wm2 = (const float*)d_in[7];
    const float* bm2 = (const float*)d_in[8];
    float* ws = (float*)d_ws;

    size_t off = 0;
    float* dinv   = ws + off; off += (size_t)BB * NN;
    float* dfill  = ws + off; off += (size_t)BB * NN;
    float* rowmax = ws + off; off += (size_t)BB * NN;
    float* hW2    = ws + off; off += (size_t)BB * NN * 16;        // 2 MB
    _Float16* y16 = (_Float16*)(ws + off);                        // 64 MB

    kA<<<dim3(BB, 16), 256, 0, stream>>>(y, y16, dinv, dfill);
    kB<<<dim3(BB, 16), 256, 0, stream>>>(y16, dinv, dfill, W1, b1, W2, hW2);
    kC<<<dim3(BB, 16), 256, 0, stream>>>(y16, dinv, dfill, hW2, b2, rowmax);
    k5_head<<<dim3(BB), 1024, 0, stream>>>(rowmax, Wm1, bm1, Wm2, bm2, (float*)d_out);
}

// Round 5
// 68.394 us; speedup vs baseline: 1.1469x; 1.1469x over previous
//
#include <hip/hip_runtime.h>
#include <math.h>

#define BB 32
#define NN 1024

typedef unsigned char u8;
typedef unsigned int u32;

// ===========================================================================
// Column-split structure, grid (B=32, 16) x 256 threads:
//   block (b,by) owns columns [by*64, by*64+64); 16 col-threads (ct, 4 cols
//   each) x 16 row-groups (rg, 64 rows each); cross-rowgroup reduce in LDS.
// kA: reads fp32 y once (128 MB): deg -> dinv/dfill, writes y8=round(255*y).
// kB/kC: re-read y8 (32 MB each) instead of fp32 y.
// ===========================================================================

// ---------------------------------------------------------------------------
// kA (pass 1): deg = colsum(y) + diag fill -> dinv, dfill;  y8 = u8(y)
// ---------------------------------------------------------------------------
__global__ __launch_bounds__(256) void kA(const float* __restrict__ y,
                                          u8* __restrict__ y8,
                                          float* __restrict__ dinv,
                                          float* __restrict__ dfill) {
    __shared__ float red[16 * 68];
    const int b = blockIdx.x, by = blockIdx.y;
    const int t = threadIdx.x, ct = t & 15, rg = t >> 4;
    const int j0 = by * 64 + ct * 4;
    const size_t boff = (size_t)b * NN * NN + (size_t)(rg * 64) * NN + j0;
    const float* base = y + boff;
    u8* ob = y8 + boff;
    float4 acc = make_float4(0.f, 0.f, 0.f, 0.f);
#pragma unroll 8
    for (int i = 0; i < 64; ++i) {
        float4 v = *(const float4*)(base + (size_t)i * NN);
        acc.x += v.x; acc.y += v.y; acc.z += v.z; acc.w += v.w;
        u32 q = (u32)(v.x * 255.f + 0.5f)
              | ((u32)(v.y * 255.f + 0.5f) << 8)
              | ((u32)(v.z * 255.f + 0.5f) << 16)
              | ((u32)(v.w * 255.f + 0.5f) << 24);
        *(u32*)(ob + (size_t)i * NN) = q;
    }
    *(float4*)&red[rg * 68 + ct * 4] = acc;
    __syncthreads();
    if (t < 64) {
        float s = 0.f;
#pragma unroll
        for (int r = 0; r < 16; ++r) s += red[r * 68 + t];
        const int j = by * 64 + t;
        const float dia = y[((size_t)b * NN + j) * NN + j];
        const float fill = (dia == 0.0f) ? 1.0f : 0.0f;
        const float deg = s + fill;
        const float dv = (deg > 0.0f) ? (1.0f / sqrtf(deg)) : 0.0f;
        dinv[b * NN + j] = dv;
        dfill[b * NN + j] = dv * fill;
    }
}

// ---------------------------------------------------------------------------
// kB (pass 2): cs[j] = dinv[j]*(sum_i dinv[i]*y[i,j] + dfill[j]);
//              hW2[j,g] = sum_f relu(cs*W1[f]+b1[f]) * W2[f,g]
// ---------------------------------------------------------------------------
__global__ __launch_bounds__(256) void kB(const u8* __restrict__ y8,
                                          const float* __restrict__ dinv,
                                          const float* __restrict__ dfill,
                                          const float* __restrict__ W1,
                                          const float* __restrict__ b1,
                                          const float* __restrict__ W2,
                                          float* __restrict__ hW2) {
    __shared__ float red[16 * 68];
    __shared__ float csb[64];
    const int b = blockIdx.x, by = blockIdx.y;
    const int t = threadIdx.x, ct = t & 15, rg = t >> 4;
    const int j0 = by * 64 + ct * 4;
    const u8* base8 = y8 + (size_t)b * NN * NN + (size_t)(rg * 64) * NN + j0;
    const float* dvp = dinv + b * NN + rg * 64;
    float4 acc = make_float4(0.f, 0.f, 0.f, 0.f);
#pragma unroll 8
    for (int i = 0; i < 64; ++i) {
        const float di = dvp[i] * (1.f / 255.f);
        const u32 q = *(const u32*)(base8 + (size_t)i * NN);
        acc.x += (float)(q & 255u) * di;
        acc.y += (float)((q >> 8) & 255u) * di;
        acc.z += (float)((q >> 16) & 255u) * di;
        acc.w += (float)(q >> 24) * di;
    }
    *(float4*)&red[rg * 68 + ct * 4] = acc;
    __syncthreads();
    if (t < 64) {
        float s = 0.f;
#pragma unroll
        for (int r = 0; r < 16; ++r) s += red[r * 68 + t];
        const int idx = b * NN + by * 64 + t;
        csb[t] = dinv[idx] * (s + dfill[idx]);
    }
    __syncthreads();
    const int qq = t >> 2, gq = t & 3;
    const float cs = csb[qq];
    float4 h = make_float4(0.f, 0.f, 0.f, 0.f);
#pragma unroll
    for (int f = 0; f < 64; ++f) {
        float x1 = fmaf(cs, W1[f], b1[f]);
        x1 = x1 > 0.f ? x1 : 0.f;
        float4 w = *(const float4*)(W2 + f * 16 + gq * 4);
        h.x += x1 * w.x; h.y += x1 * w.y; h.z += x1 * w.z; h.w += x1 * w.w;
    }
    const int j = by * 64 + qq;
    *(float4*)(hW2 + ((size_t)(b * NN + j)) * 16 + gq * 4) = h;
}

// ---------------------------------------------------------------------------
// kC (pass 3): out2[j,g] = dinv[j]*(sum_i dinv[i]*y[i,j]*hW2[i,g]
//                                   + dfill[j]*hW2[j,g]) + b2[g];
//              rowmax[j] = max_g out2[j,g]
// LDS reduce layout: float4 slot (rg*256 + ct*16 + p), p = (g+ct+rg)&15
// ---------------------------------------------------------------------------
__global__ __launch_bounds__(256) void kC(const u8* __restrict__ y8,
                                          const float* __restrict__ dinv,
                                          const float* __restrict__ dfill,
                                          const float* __restrict__ hW2,
                                          const float* __restrict__ b2,
                                          float* __restrict__ rowmax) {
    __shared__ float red[16 * 16 * 16 * 4];   // 64 KB
    const int b = blockIdx.x, by = blockIdx.y;
    const int t = threadIdx.x, ct = t & 15, rg = t >> 4;
    const int j0 = by * 64 + ct * 4;
    const u8* base8 = y8 + (size_t)b * NN * NN + (size_t)(rg * 64) * NN + j0;
    const float* dvp = dinv + b * NN + rg * 64;
    const float* hp = hW2 + ((size_t)(b * NN + rg * 64)) * 16;

    float4 acc[16];
#pragma unroll
    for (int g = 0; g < 16; ++g) acc[g] = make_float4(0.f, 0.f, 0.f, 0.f);

#pragma unroll 4
    for (int i = 0; i < 64; ++i) {
        const u32 qv = *(const u32*)(base8 + (size_t)i * NN);
        const float diq = dvp[i] * (1.f / 255.f);
        const float4* hr = (const float4*)(hp + (size_t)i * 16);
        float4 h0 = hr[0], h1 = hr[1], h2 = hr[2], h3 = hr[3];
        float4 a;
        a.x = (float)(qv & 255u) * diq;
        a.y = (float)((qv >> 8) & 255u) * diq;
        a.z = (float)((qv >> 16) & 255u) * diq;
        a.w = (float)(qv >> 24) * diq;
#define STEP(G, HS) acc[G].x += a.x * (HS); acc[G].y += a.y * (HS); \
                    acc[G].z += a.z * (HS); acc[G].w += a.w * (HS);
        STEP(0, h0.x)  STEP(1, h0.y)  STEP(2, h0.z)  STEP(3, h0.w)
        STEP(4, h1.x)  STEP(5, h1.y)  STEP(6, h1.z)  STEP(7, h1.w)
        STEP(8, h2.x)  STEP(9, h2.y)  STEP(10, h2.z) STEP(11, h2.w)
        STEP(12, h3.x) STEP(13, h3.y) STEP(14, h3.z) STEP(15, h3.w)
#undef STEP
    }
#pragma unroll
    for (int g = 0; g < 16; ++g) {
        const int p = (g + ct + rg) & 15;
        *(float4*)&red[(rg * 256 + ct * 16 + p) * 4] = acc[g];
    }
    __syncthreads();
    const int q = t >> 2, gq = t & 3;
    const int cti = q >> 2, kk = q & 3;
    const int j = by * 64 + q;
    const int idx = b * NN + j;
    const float dv = dinv[idx], df = dfill[idx];
    const float* hj = hW2 + (size_t)idx * 16;
    float m = -3.4e38f;
#pragma unroll
    for (int e = 0; e < 4; ++e) {
        const int g = gq * 4 + e;
        float s = 0.f;
#pragma unroll
        for (int r = 0; r < 16; ++r) {
            const int p = (g + cti + r) & 15;
            s += red[(r * 256 + cti * 16 + p) * 4 + kk];
        }
        const float ov = dv * (s + df * hj[g]) + b2[g];
        m = fmaxf(m, ov);
    }
    m = fmaxf(m, __shfl_xor(m, 1));
    m = fmaxf(m, __shfl_xor(m, 2));
    if ((t & 3) == 0) rowmax[idx] = m;
}

// ---------------------------------------------------------------------------
// k5: head — (B,N) @ Wm1(N,32) + bm1 -> @ Wm2(32,16) + bm2.  1 block / batch.
// ---------------------------------------------------------------------------
__global__ __launch_bounds__(1024) void k5_head(const float* __restrict__ rowmax,
                                                const float* __restrict__ Wm1,
                                                const float* __restrict__ bm1,
                                                const float* __restrict__ Wm2,
                                                const float* __restrict__ bm2,
                                                float* __restrict__ out) {
    __shared__ float sm[NN];
    __shared__ float p[32 * 32];
    __shared__ float z[32];
    const int b = blockIdx.x, t = threadIdx.x;
    sm[t] = rowmax[(size_t)b * NN + t];
    __syncthreads();
    const int k = t & 31, c = t >> 5;
    float acc = 0.f;
#pragma unroll 8
    for (int qq = 0; qq < 32; ++qq) {
        const int j = c * 32 + qq;
        acc += sm[j] * Wm1[j * 32 + k];
    }
    p[c * 32 + k] = acc;
    __syncthreads();
    if (t < 32) {
        float s = 0.f;
#pragma unroll
        for (int c2 = 0; c2 < 32; ++c2) s += p[c2 * 32 + t];
        z[t] = s + bm1[t];
    }
    __syncthreads();
    if (t < 16) {
        float s = 0.f;
#pragma unroll
        for (int k2 = 0; k2 < 32; ++k2) s += z[k2] * Wm2[k2 * 16 + t];
        out[b * 16 + t] = s + bm2[t];
    }
}

// ---------------------------------------------------------------------------
extern "C" void kernel_launch(void* const* d_in, const int* in_sizes, int n_in,
                              void* d_out, int out_size, void* d_ws, size_t ws_size,
                              hipStream_t stream) {
    const float* y   = (const float*)d_in[0];
    const float* W1  = (const float*)d_in[1];
    const float* b1  = (const float*)d_in[2];
    const float* W2  = (const float*)d_in[3];
    const float* b2  = (const float*)d_in[4];
    const float* Wm1 = (const float*)d_in[5];
    const float* bm1 = (const float*)d_in[6];
    const float* Wm2 = (const float*)d_in[7];
    const float* bm2 = (const float*)d_in[8];
    float* ws = (float*)d_ws;

    size_t off = 0;
    float* dinv   = ws + off; off += (size_t)BB * NN;
    float* dfill  = ws + off; off += (size_t)BB * NN;
    float* rowmax = ws + off; off += (size_t)BB * NN;
    float* hW2    = ws + off; off += (size_t)BB * NN * 16;   // 2 MB
    u8* y8        = (u8*)(ws + off);                         // 32 MB

    kA<<<dim3(BB, 16), 256, 0, stream>>>(y, y8, dinv, dfill);
    kB<<<dim3(BB, 16), 256, 0, stream>>>(y8, dinv, dfill, W1, b1, W2, hW2);
    kC<<<dim3(BB, 16), 256, 0, stream>>>(y8, dinv, dfill, hW2, b2, rowmax);
    k5_head<<<dim3(BB), 1024, 0, stream>>>(rowmax, Wm1, bm1, Wm2, bm2, (float*)d_out);
}